// Round 1
// baseline (8552.595 us; speedup 1.0000x reference)
//
#include <hip/hip_runtime.h>
#include <hip/hip_fp16.h>

// SoftRR: n=1024, m=8192, rounds=8, TAU=1.0
//   scan over 8192 rows (V tiled x8):
//     y = softmax((row - min(row) + 1) * c);  c = (1-y)*c
//   pi[i][j] = sum over rounds of y
//
// Sequential scan -> single workgroup (1024 thr, 16 waves), one LDS barrier
// per step.  Max-subtraction dropped (z in (0,~13] after log2e premul, no
// overflow), so only a SUM block-reduction per step.
// a = (V - rowmin + 1)*log2e precomputed in fp16 (halves traffic, 2%-of-max
// tolerance makes fp16 safe).  pi accumulated in fp16 in ws, converted to
// f32 at the end.  Fallback path (tiny ws) reads V f32 directly and RMWs
// d_out in f32.

#define N_ROWS 1024
#define M_COLS 8192
#define STEPS  8192
#define LOG2E  1.4426950408889634f

using half8 = __attribute__((ext_vector_type(8))) _Float16;

__device__ __forceinline__ float fast_exp2(float x) {
#if __has_builtin(__builtin_amdgcn_exp2f)
  return __builtin_amdgcn_exp2f(x);
#else
  return exp2f(x);
#endif
}
__device__ __forceinline__ float fast_rcp(float x) {
#if __has_builtin(__builtin_amdgcn_rcpf)
  return __builtin_amdgcn_rcpf(x);
#else
  return 1.0f / x;
#endif
}

// ---------------- rowmin: one block per row ----------------
__global__ void softrr_rowmin(const float* __restrict__ V, float* __restrict__ rmin) {
  const int row = blockIdx.x;
  const float* p = V + (size_t)row * M_COLS;
  float m = 1e30f;
  for (int j = threadIdx.x; j < M_COLS; j += 256) m = fminf(m, p[j]);
#pragma unroll
  for (int off = 32; off; off >>= 1) m = fminf(m, __shfl_xor(m, off, 64));
  __shared__ float sm[4];
  if ((threadIdx.x & 63) == 0) sm[threadIdx.x >> 6] = m;
  __syncthreads();
  if (threadIdx.x == 0) {
    rmin[row] = fminf(fminf(sm[0], sm[1]), fminf(sm[2], sm[3]));
  }
}

// ---------------- prep: a = (V - rowmin + 1) * log2e, fp16 ----------------
__global__ void softrr_prep(const float* __restrict__ V, const float* __restrict__ rmin,
                            __half* __restrict__ A) {
  const int idx8 = blockIdx.x * 256 + threadIdx.x;   // 1M half8 groups
  const int row = idx8 >> 10;                        // 1024 half8 per row
  const float mn = rmin[row];
  const float4* v4 = (const float4*)V;
  float4 va = v4[2 * idx8];
  float4 vb = v4[2 * idx8 + 1];
  half8 o;
  o[0] = (_Float16)((va.x - mn + 1.0f) * LOG2E);
  o[1] = (_Float16)((va.y - mn + 1.0f) * LOG2E);
  o[2] = (_Float16)((va.z - mn + 1.0f) * LOG2E);
  o[3] = (_Float16)((va.w - mn + 1.0f) * LOG2E);
  o[4] = (_Float16)((vb.x - mn + 1.0f) * LOG2E);
  o[5] = (_Float16)((vb.y - mn + 1.0f) * LOG2E);
  o[6] = (_Float16)((vb.z - mn + 1.0f) * LOG2E);
  o[7] = (_Float16)((vb.w - mn + 1.0f) * LOG2E);
  ((half8*)A)[idx8] = o;
}

// ---------------- main sequential scan (path A: fp16 a + fp16 pi) ----------------
__global__ void __launch_bounds__(1024) softrr_scan_a(const __half* __restrict__ Ah,
                                                      __half* __restrict__ PIh) {
  const int t = threadIdx.x;          // 0..1023, owns cols 8t..8t+7
  const int wave = t >> 6;
  const int lane = t & 63;
  __shared__ float partials[2][16];

  const half8* __restrict__ A8 = (const half8*)Ah;
  half8* __restrict__ P8 = (half8*)PIh;

  float c[8];
#pragma unroll
  for (int k = 0; k < 8; ++k) c[k] = 1.0f;

  half8 a_cur = A8[t];   // row 0
  half8 p_cur;           // pi prefetch (valid from round 1 on)

  for (int s = 0; s < STEPS; ++s) {
    const int i = s & (N_ROWS - 1);
    const int r = s >> 10;
    const int in_ = (s + 1) & (N_ROWS - 1);

    // prefetch next a-row (row known in advance; wraps harmlessly at end)
    half8 a_next = A8[in_ * 1024 + t];

    float e[8];
    float l = 0.0f;
#pragma unroll
    for (int k = 0; k < 8; ++k) {
      float z = (float)a_cur[k] * c[k];   // a premultiplied by log2e
      e[k] = fast_exp2(z);
      l += e[k];
    }
    // wave sum
#pragma unroll
    for (int off = 32; off; off >>= 1) l += __shfl_xor(l, off, 64);
    if (lane == 0) partials[s & 1][wave] = l;
    __syncthreads();   // single barrier per step (parity double-buffer)

    float S = 0.0f;
#pragma unroll
    for (int w = 0; w < 16; ++w) S += partials[s & 1][w];
    const float Sinv = fast_rcp(S);

    half8 ov;
#pragma unroll
    for (int k = 0; k < 8; ++k) {
      float y = e[k] * Sinv;
      c[k] = __builtin_fmaf(-y, c[k], c[k]);   // c *= (1 - y)
      float acc = y;
      if (r > 0) acc += (float)p_cur[k];
      ov[k] = (_Float16)acc;
    }
    P8[i * 1024 + t] = ov;

    a_cur = a_next;
    // prefetch pi row for next step (written 1024 steps ago by this thread)
    p_cur = P8[in_ * 1024 + t];
  }
}

// ---------------- epilogue: fp16 pi -> f32 out ----------------
__global__ void softrr_cvt(const __half* __restrict__ PIh, float* __restrict__ out) {
  const int idx8 = blockIdx.x * 256 + threadIdx.x;
  half8 p = ((const half8*)PIh)[idx8];
  float4 o1 = make_float4((float)p[0], (float)p[1], (float)p[2], (float)p[3]);
  float4 o2 = make_float4((float)p[4], (float)p[5], (float)p[6], (float)p[7]);
  ((float4*)out)[2 * idx8] = o1;
  ((float4*)out)[2 * idx8 + 1] = o2;
}

// ---------------- fallback scan (path B: f32 V + f32 out RMW) ----------------
__global__ void __launch_bounds__(1024) softrr_scan_b(const float* __restrict__ V,
                                                      const float* __restrict__ rmin,
                                                      float* __restrict__ out) {
  const int t = threadIdx.x;
  const int wave = t >> 6;
  const int lane = t & 63;
  __shared__ float partials[2][16];
  __shared__ float smin[N_ROWS];
  smin[t] = rmin[t];
  __syncthreads();

  const float4* __restrict__ V4 = (const float4*)V;
  float4* O4 = (float4*)out;

  float c[8];
#pragma unroll
  for (int k = 0; k < 8; ++k) c[k] = 1.0f;

  float4 va = V4[2 * t], vb = V4[2 * t + 1];
  float4 pa, pb;

  for (int s = 0; s < STEPS; ++s) {
    const int i = s & (N_ROWS - 1);
    const int r = s >> 10;
    const int in_ = (s + 1) & (N_ROWS - 1);

    float4 van = V4[in_ * 2048 + 2 * t];
    float4 vbn = V4[in_ * 2048 + 2 * t + 1];

    const float mn = smin[i];
    const float base = (1.0f - mn) * LOG2E;

    float vv[8] = {va.x, va.y, va.z, va.w, vb.x, vb.y, vb.z, vb.w};
    float e[8];
    float l = 0.0f;
#pragma unroll
    for (int k = 0; k < 8; ++k) {
      float zb = __builtin_fmaf(vv[k], LOG2E, base);  // (v - mn + 1)*log2e
      e[k] = fast_exp2(zb * c[k]);
      l += e[k];
    }
#pragma unroll
    for (int off = 32; off; off >>= 1) l += __shfl_xor(l, off, 64);
    if (lane == 0) partials[s & 1][wave] = l;
    __syncthreads();

    float S = 0.0f;
#pragma unroll
    for (int w = 0; w < 16; ++w) S += partials[s & 1][w];
    const float Sinv = fast_rcp(S);

    float po[8] = {pa.x, pa.y, pa.z, pa.w, pb.x, pb.y, pb.z, pb.w};
    float o[8];
#pragma unroll
    for (int k = 0; k < 8; ++k) {
      float y = e[k] * Sinv;
      c[k] = __builtin_fmaf(-y, c[k], c[k]);
      o[k] = (r > 0) ? (po[k] + y) : y;
    }
    O4[i * 2048 + 2 * t]     = make_float4(o[0], o[1], o[2], o[3]);
    O4[i * 2048 + 2 * t + 1] = make_float4(o[4], o[5], o[6], o[7]);

    va = van; vb = vbn;
    pa = O4[in_ * 2048 + 2 * t];
    pb = O4[in_ * 2048 + 2 * t + 1];
  }
}

extern "C" void kernel_launch(void* const* d_in, const int* in_sizes, int n_in,
                              void* d_out, int out_size, void* d_ws, size_t ws_size,
                              hipStream_t stream) {
  const float* V = (const float*)d_in[0];
  float* out = (float*)d_out;
  float* rmin = (float*)d_ws;

  const size_t A_BYTES = (size_t)N_ROWS * M_COLS * 2;  // 16 MB
  const size_t need = 4096 + A_BYTES + A_BYTES;        // rowmin + a + pi

  if (ws_size >= need) {
    __half* A  = (__half*)((char*)d_ws + 4096);
    __half* PI = (__half*)((char*)d_ws + 4096 + A_BYTES);
    softrr_rowmin<<<N_ROWS, 256, 0, stream>>>(V, rmin);
    softrr_prep<<<4096, 256, 0, stream>>>(V, rmin, A);
    softrr_scan_a<<<1, 1024, 0, stream>>>(A, PI);
    softrr_cvt<<<4096, 256, 0, stream>>>(PI, out);
  } else {
    softrr_rowmin<<<N_ROWS, 256, 0, stream>>>(V, rmin);
    softrr_scan_b<<<1, 1024, 0, stream>>>(V, rmin, out);
  }
}

// Round 3
// 8426.374 us; speedup vs baseline: 1.0150x; 1.0150x over previous
//
#include <hip/hip_runtime.h>
#include <hip/hip_fp16.h>

// SoftRR: n=1024, m=8192, rounds=8, TAU=1.0
//   scan over 8192 rows (V tiled x8):
//     y = softmax((row - min(row) + 1) * c);  c = (1-y)*c
//   pi[i][j] = sum over rounds of y
//
// R3 = R2 with the cvt_pkrtz return-type fix (bit_cast __fp16x2 -> _Float16x2).
// Single-workgroup scan, 512 thr (8 waves), 16 cols/thread.
//  - barrier = inline-asm "s_waitcnt lgkmcnt(0); s_barrier" so the compiler's
//    vmcnt(0) drain (full HBM latency per step) is NOT inserted; global
//    prefetches stay in flight across the barrier.
//  - wave reduce + cross-wave reduce via DPP adds (VALU pipe), not
//    ds_swizzle / ds_read_b128 (LDS pipe).
//  - pi accumulated with v_cvt_pkrtz + v_pk_add_f16; c stays f32 in regs.

#define N_ROWS 1024
#define M_COLS 8192
#define STEPS  8192
#define LOG2E  1.4426950408889634f

using half8  = __attribute__((ext_vector_type(8))) _Float16;
using half2v = __attribute__((ext_vector_type(2))) _Float16;

__device__ __forceinline__ float fast_exp2(float x) {
#if __has_builtin(__builtin_amdgcn_exp2f)
  return __builtin_amdgcn_exp2f(x);
#else
  return exp2f(x);
#endif
}
__device__ __forceinline__ float fast_rcp(float x) {
#if __has_builtin(__builtin_amdgcn_rcpf)
  return __builtin_amdgcn_rcpf(x);
#else
  return 1.0f / x;
#endif
}
__device__ __forceinline__ half2v pack_f16(float y0, float y1) {
  return __builtin_bit_cast(half2v, __builtin_amdgcn_cvt_pkrtz(y0, y1));
}

template <int CTRL>
__device__ __forceinline__ float dpp_add(float x) {
  int yi = __builtin_amdgcn_update_dpp(0, __builtin_bit_cast(int, x),
                                       CTRL, 0xf, 0xf, true);
  return x + __builtin_bit_cast(float, yi);
}

// full 64-lane sum; result valid in lane 63
__device__ __forceinline__ float wave_sum_to_lane63(float x) {
  x = dpp_add<0x111>(x);  // row_shr:1
  x = dpp_add<0x112>(x);  // row_shr:2
  x = dpp_add<0x114>(x);  // row_shr:4
  x = dpp_add<0x118>(x);  // row_shr:8   -> lane15 of each row = row sum
  x = dpp_add<0x142>(x);  // row_bcast15
  x = dpp_add<0x143>(x);  // row_bcast31 -> lane63 = total
  return x;
}

// barrier WITHOUT vmcnt drain: only LDS ops must be visible across it
#define BAR_LDS_ONLY() asm volatile("s_waitcnt lgkmcnt(0)\n\ts_barrier" ::: "memory")

// ---------------- rowmin: one block per row ----------------
__global__ void softrr_rowmin(const float* __restrict__ V, float* __restrict__ rmin) {
  const int row = blockIdx.x;
  const float* p = V + (size_t)row * M_COLS;
  float m = 1e30f;
  for (int j = threadIdx.x; j < M_COLS; j += 256) m = fminf(m, p[j]);
#pragma unroll
  for (int off = 32; off; off >>= 1) m = fminf(m, __shfl_xor(m, off, 64));
  __shared__ float sm[4];
  if ((threadIdx.x & 63) == 0) sm[threadIdx.x >> 6] = m;
  __syncthreads();
  if (threadIdx.x == 0) {
    rmin[row] = fminf(fminf(sm[0], sm[1]), fminf(sm[2], sm[3]));
  }
}

// ---------------- prep: a = (V - rowmin + 1) * log2e, fp16 ----------------
__global__ void softrr_prep(const float* __restrict__ V, const float* __restrict__ rmin,
                            __half* __restrict__ A) {
  const int idx8 = blockIdx.x * 256 + threadIdx.x;   // 1M half8 groups
  const int row = idx8 >> 10;                        // 1024 half8 per row
  const float mn = rmin[row];
  const float4* v4 = (const float4*)V;
  float4 va = v4[2 * idx8];
  float4 vb = v4[2 * idx8 + 1];
  half8 o;
  o[0] = (_Float16)((va.x - mn + 1.0f) * LOG2E);
  o[1] = (_Float16)((va.y - mn + 1.0f) * LOG2E);
  o[2] = (_Float16)((va.z - mn + 1.0f) * LOG2E);
  o[3] = (_Float16)((va.w - mn + 1.0f) * LOG2E);
  o[4] = (_Float16)((vb.x - mn + 1.0f) * LOG2E);
  o[5] = (_Float16)((vb.y - mn + 1.0f) * LOG2E);
  o[6] = (_Float16)((vb.z - mn + 1.0f) * LOG2E);
  o[7] = (_Float16)((vb.w - mn + 1.0f) * LOG2E);
  ((half8*)A)[idx8] = o;
}

// ---------------- main sequential scan: 512 thr, 16 cols/thread ----------------
__global__ void __launch_bounds__(512) softrr_scan_a(const __half* __restrict__ Ah,
                                                     __half* __restrict__ PIh) {
  const int t = threadIdx.x;          // 0..511, owns cols 16t..16t+15
  const int wave = t >> 6;            // 0..7
  const int lane = t & 63;
  __shared__ float sP[2][8];

  const half8* __restrict__ A8 = (const half8*)Ah;
  half8* __restrict__ P8 = (half8*)PIh;

  float c[16];
#pragma unroll
  for (int k = 0; k < 16; ++k) c[k] = 1.0f;

  half8 a0 = A8[2 * t];        // row 0
  half8 a1 = A8[2 * t + 1];
  half8 p0, p1;                // pi prefetch (valid from round 1 on)

  for (int s = 0; s < STEPS; ++s) {
    const int i   = s & (N_ROWS - 1);
    const int r   = s >> 10;
    const int in_ = (s + 1) & (N_ROWS - 1);
    const int par = s & 1;

    // prefetch next a-row (in flight across the whole step; barrier does NOT
    // wait on it)
    half8 an0 = A8[in_ * 1024 + 2 * t];
    half8 an1 = A8[in_ * 1024 + 2 * t + 1];

    float e[16];
#pragma unroll
    for (int k = 0; k < 8; ++k) {
      e[k]     = fast_exp2((float)a0[k] * c[k]);
      e[8 + k] = fast_exp2((float)a1[k] * c[8 + k]);
    }
    // pairwise tree sum (short dep chain)
    float l = (((e[0] + e[1]) + (e[2] + e[3])) + ((e[4] + e[5]) + (e[6] + e[7])))
            + (((e[8] + e[9]) + (e[10] + e[11])) + ((e[12] + e[13]) + (e[14] + e[15])));

    l = wave_sum_to_lane63(l);
    if (lane == 63) sP[par][wave] = l;
    BAR_LDS_ONLY();

    // cross-wave: lanes 0..7 read the 8 partials, 3 DPP stages -> lane 7
    float x = (lane < 8) ? sP[par][lane] : 0.0f;
    x = dpp_add<0x111>(x);
    x = dpp_add<0x112>(x);
    x = dpp_add<0x114>(x);
    const float S = __builtin_bit_cast(
        float, __builtin_amdgcn_readlane(__builtin_bit_cast(int, x), 7));
    const float Sinv = fast_rcp(S);

    half8 o0, o1;
#pragma unroll
    for (int k = 0; k < 8; k += 2) {
      float y0 = e[k] * Sinv;
      float y1 = e[k + 1] * Sinv;
      c[k]     = __builtin_fmaf(-y0, c[k], c[k]);
      c[k + 1] = __builtin_fmaf(-y1, c[k + 1], c[k + 1]);
      half2v h = pack_f16(y0, y1);
      o0[k] = h[0]; o0[k + 1] = h[1];
    }
#pragma unroll
    for (int k = 0; k < 8; k += 2) {
      float y0 = e[8 + k] * Sinv;
      float y1 = e[8 + k + 1] * Sinv;
      c[8 + k]     = __builtin_fmaf(-y0, c[8 + k], c[8 + k]);
      c[8 + k + 1] = __builtin_fmaf(-y1, c[8 + k + 1], c[8 + k + 1]);
      half2v h = pack_f16(y0, y1);
      o1[k] = h[0]; o1[k + 1] = h[1];
    }
    if (r > 0) {            // uniform branch; v_pk_add_f16
      o0 = o0 + p0;
      o1 = o1 + p1;
    }
    P8[i * 1024 + 2 * t]     = o0;
    P8[i * 1024 + 2 * t + 1] = o1;

    a0 = an0; a1 = an1;
    // prefetch pi row for next step (written 1024 steps ago by this thread)
    p0 = P8[in_ * 1024 + 2 * t];
    p1 = P8[in_ * 1024 + 2 * t + 1];
  }
}

// ---------------- epilogue: fp16 pi -> f32 out ----------------
__global__ void softrr_cvt(const __half* __restrict__ PIh, float* __restrict__ out) {
  const int idx8 = blockIdx.x * 256 + threadIdx.x;
  half8 p = ((const half8*)PIh)[idx8];
  float4 o1 = make_float4((float)p[0], (float)p[1], (float)p[2], (float)p[3]);
  float4 o2 = make_float4((float)p[4], (float)p[5], (float)p[6], (float)p[7]);
  ((float4*)out)[2 * idx8] = o1;
  ((float4*)out)[2 * idx8 + 1] = o2;
}

// ---------------- fallback scan (f32 V + f32 out RMW, small ws) ----------------
__global__ void __launch_bounds__(1024) softrr_scan_b(const float* __restrict__ V,
                                                      const float* __restrict__ rmin,
                                                      float* __restrict__ out) {
  const int t = threadIdx.x;
  const int wave = t >> 6;
  const int lane = t & 63;
  __shared__ float partials[2][16];
  __shared__ float smin[N_ROWS];
  smin[t] = rmin[t];
  __syncthreads();

  const float4* __restrict__ V4 = (const float4*)V;
  float4* O4 = (float4*)out;

  float c[8];
#pragma unroll
  for (int k = 0; k < 8; ++k) c[k] = 1.0f;

  float4 va = V4[2 * t], vb = V4[2 * t + 1];
  float4 pa, pb;

  for (int s = 0; s < STEPS; ++s) {
    const int i = s & (N_ROWS - 1);
    const int r = s >> 10;
    const int in_ = (s + 1) & (N_ROWS - 1);

    float4 van = V4[in_ * 2048 + 2 * t];
    float4 vbn = V4[in_ * 2048 + 2 * t + 1];

    const float mn = smin[i];
    const float base = (1.0f - mn) * LOG2E;

    float vv[8] = {va.x, va.y, va.z, va.w, vb.x, vb.y, vb.z, vb.w};
    float e[8];
    float l = 0.0f;
#pragma unroll
    for (int k = 0; k < 8; ++k) {
      float zb = __builtin_fmaf(vv[k], LOG2E, base);
      e[k] = fast_exp2(zb * c[k]);
      l += e[k];
    }
#pragma unroll
    for (int off = 32; off; off >>= 1) l += __shfl_xor(l, off, 64);
    if (lane == 0) partials[s & 1][wave] = l;
    __syncthreads();

    float S = 0.0f;
#pragma unroll
    for (int w = 0; w < 16; ++w) S += partials[s & 1][w];
    const float Sinv = fast_rcp(S);

    float po[8] = {pa.x, pa.y, pa.z, pa.w, pb.x, pb.y, pb.z, pb.w};
    float o[8];
#pragma unroll
    for (int k = 0; k < 8; ++k) {
      float y = e[k] * Sinv;
      c[k] = __builtin_fmaf(-y, c[k], c[k]);
      o[k] = (r > 0) ? (po[k] + y) : y;
    }
    O4[i * 2048 + 2 * t]     = make_float4(o[0], o[1], o[2], o[3]);
    O4[i * 2048 + 2 * t + 1] = make_float4(o[4], o[5], o[6], o[7]);

    va = van; vb = vbn;
    pa = O4[in_ * 2048 + 2 * t];
    pb = O4[in_ * 2048 + 2 * t + 1];
  }
}

extern "C" void kernel_launch(void* const* d_in, const int* in_sizes, int n_in,
                              void* d_out, int out_size, void* d_ws, size_t ws_size,
                              hipStream_t stream) {
  const float* V = (const float*)d_in[0];
  float* out = (float*)d_out;
  float* rmin = (float*)d_ws;

  const size_t A_BYTES = (size_t)N_ROWS * M_COLS * 2;  // 16 MB
  const size_t need = 4096 + A_BYTES + A_BYTES;        // rowmin + a + pi

  if (ws_size >= need) {
    __half* A  = (__half*)((char*)d_ws + 4096);
    __half* PI = (__half*)((char*)d_ws + 4096 + A_BYTES);
    softrr_rowmin<<<N_ROWS, 256, 0, stream>>>(V, rmin);
    softrr_prep<<<4096, 256, 0, stream>>>(V, rmin, A);
    softrr_scan_a<<<1, 512, 0, stream>>>(A, PI);
    softrr_cvt<<<4096, 256, 0, stream>>>(PI, out);
  } else {
    softrr_rowmin<<<N_ROWS, 256, 0, stream>>>(V, rmin);
    softrr_scan_b<<<1, 1024, 0, stream>>>(V, rmin, out);
  }
}

// Round 4
// 4970.790 us; speedup vs baseline: 1.7206x; 1.6952x over previous
//
#include <hip/hip_runtime.h>
#include <hip/hip_fp16.h>

// SoftRR: n=1024, m=8192, rounds=8, TAU=1.0
//   scan over 8192 rows (V tiled x8):
//     y = softmax((row - min(row) + 1) * c);  c = (1-y)*c
//   pi[i][j] = sum over rounds of y
//
// R4: store-only scan. R1/R3 were serialized by the compiler's mandatory
// vmcnt(0) ordering of `load PI` after `store PI` (unprovable aliasing) —
// which also drained the A prefetches every step. Now the scan writes each
// step's y row consecutively into R[8192][8192] f16 (128 MiB ws) and never
// reads it; a full-chip epilogue sums the 8 round-slices into out (f32).
// A-rows are prefetched 2 steps ahead; reductions are DPP (VALU pipe);
// barrier is lgkmcnt-only.

#define N_ROWS 1024
#define M_COLS 8192
#define STEPS  8192
#define LOG2E  1.4426950408889634f

using half8  = __attribute__((ext_vector_type(8))) _Float16;
using half2v = __attribute__((ext_vector_type(2))) _Float16;

__device__ __forceinline__ float fast_exp2(float x) {
#if __has_builtin(__builtin_amdgcn_exp2f)
  return __builtin_amdgcn_exp2f(x);
#else
  return exp2f(x);
#endif
}
__device__ __forceinline__ float fast_rcp(float x) {
#if __has_builtin(__builtin_amdgcn_rcpf)
  return __builtin_amdgcn_rcpf(x);
#else
  return 1.0f / x;
#endif
}
__device__ __forceinline__ half2v pack_f16(float y0, float y1) {
  return __builtin_bit_cast(half2v, __builtin_amdgcn_cvt_pkrtz(y0, y1));
}

template <int CTRL>
__device__ __forceinline__ float dpp_add(float x) {
  int yi = __builtin_amdgcn_update_dpp(0, __builtin_bit_cast(int, x),
                                       CTRL, 0xf, 0xf, true);
  return x + __builtin_bit_cast(float, yi);
}

// full 64-lane sum; result valid in lane 63
__device__ __forceinline__ float wave_sum_to_lane63(float x) {
  x = dpp_add<0x111>(x);  // row_shr:1
  x = dpp_add<0x112>(x);  // row_shr:2
  x = dpp_add<0x114>(x);  // row_shr:4
  x = dpp_add<0x118>(x);  // row_shr:8   -> lane15 of each row = row sum
  x = dpp_add<0x142>(x);  // row_bcast15
  x = dpp_add<0x143>(x);  // row_bcast31 -> lane63 = total
  return x;
}

// barrier WITHOUT vmcnt drain: only LDS ops must be visible across it
#define BAR_LDS_ONLY() asm volatile("s_waitcnt lgkmcnt(0)\n\ts_barrier" ::: "memory")

// ---------------- rowmin: one block per row ----------------
__global__ void softrr_rowmin(const float* __restrict__ V, float* __restrict__ rmin) {
  const int row = blockIdx.x;
  const float* p = V + (size_t)row * M_COLS;
  float m = 1e30f;
  for (int j = threadIdx.x; j < M_COLS; j += 256) m = fminf(m, p[j]);
#pragma unroll
  for (int off = 32; off; off >>= 1) m = fminf(m, __shfl_xor(m, off, 64));
  __shared__ float sm[4];
  if ((threadIdx.x & 63) == 0) sm[threadIdx.x >> 6] = m;
  __syncthreads();
  if (threadIdx.x == 0) {
    rmin[row] = fminf(fminf(sm[0], sm[1]), fminf(sm[2], sm[3]));
  }
}

// ---------------- prep: a = (V - rowmin + 1) * log2e, fp16 ----------------
__global__ void softrr_prep(const float* __restrict__ V, const float* __restrict__ rmin,
                            __half* __restrict__ A) {
  const int idx8 = blockIdx.x * 256 + threadIdx.x;   // 1M half8 groups
  const int row = idx8 >> 10;                        // 1024 half8 per row
  const float mn = rmin[row];
  const float4* v4 = (const float4*)V;
  float4 va = v4[2 * idx8];
  float4 vb = v4[2 * idx8 + 1];
  half8 o;
  o[0] = (_Float16)((va.x - mn + 1.0f) * LOG2E);
  o[1] = (_Float16)((va.y - mn + 1.0f) * LOG2E);
  o[2] = (_Float16)((va.z - mn + 1.0f) * LOG2E);
  o[3] = (_Float16)((va.w - mn + 1.0f) * LOG2E);
  o[4] = (_Float16)((vb.x - mn + 1.0f) * LOG2E);
  o[5] = (_Float16)((vb.y - mn + 1.0f) * LOG2E);
  o[6] = (_Float16)((vb.z - mn + 1.0f) * LOG2E);
  o[7] = (_Float16)((vb.w - mn + 1.0f) * LOG2E);
  ((half8*)A)[idx8] = o;
}

// ---------------- main scan, store-only: 512 thr, 16 cols/thread ----------------
// Writes y for step s at R8[s*1024 + 2t{,+1}]; never reads R.
__global__ void __launch_bounds__(512) softrr_scan_nor(const __half* __restrict__ Ah,
                                                       __half* __restrict__ Rh) {
  const int t = threadIdx.x;          // 0..511, owns cols 16t..16t+15
  const int wave = t >> 6;            // 0..7
  const int lane = t & 63;
  __shared__ float sP[2][8];

  const half8* __restrict__ A8 = (const half8*)Ah;
  half8* __restrict__ R8 = (half8*)Rh;

  float c[16];
#pragma unroll
  for (int k = 0; k < 16; ++k) c[k] = 1.0f;

  // A-row prefetch ring, 2 steps deep
  half8 a_cur0 = A8[2 * t];
  half8 a_cur1 = A8[2 * t + 1];
  half8 a_nx0  = A8[1024 + 2 * t];
  half8 a_nx1  = A8[1024 + 2 * t + 1];

  for (int s = 0; s < STEPS; ++s) {
    const int ld  = (s + 2) & (N_ROWS - 1);   // row to prefetch (2 ahead)
    const int par = s & 1;

    half8 an0 = A8[ld * 1024 + 2 * t];
    half8 an1 = A8[ld * 1024 + 2 * t + 1];

    float e[16];
#pragma unroll
    for (int k = 0; k < 8; ++k) {
      e[k]     = fast_exp2((float)a_cur0[k] * c[k]);
      e[8 + k] = fast_exp2((float)a_cur1[k] * c[8 + k]);
    }
    float l = (((e[0] + e[1]) + (e[2] + e[3])) + ((e[4] + e[5]) + (e[6] + e[7])))
            + (((e[8] + e[9]) + (e[10] + e[11])) + ((e[12] + e[13]) + (e[14] + e[15])));

    l = wave_sum_to_lane63(l);
    if (lane == 63) sP[par][wave] = l;
    BAR_LDS_ONLY();

    float x = (lane < 8) ? sP[par][lane] : 0.0f;
    x = dpp_add<0x111>(x);
    x = dpp_add<0x112>(x);
    x = dpp_add<0x114>(x);
    const float S = __builtin_bit_cast(
        float, __builtin_amdgcn_readlane(__builtin_bit_cast(int, x), 7));
    const float Sinv = fast_rcp(S);

    half8 o0, o1;
#pragma unroll
    for (int k = 0; k < 8; k += 2) {
      float y0 = e[k] * Sinv;
      float y1 = e[k + 1] * Sinv;
      c[k]     = __builtin_fmaf(-y0, c[k], c[k]);
      c[k + 1] = __builtin_fmaf(-y1, c[k + 1], c[k + 1]);
      half2v h = pack_f16(y0, y1);
      o0[k] = h[0]; o0[k + 1] = h[1];
    }
#pragma unroll
    for (int k = 0; k < 8; k += 2) {
      float y0 = e[8 + k] * Sinv;
      float y1 = e[8 + k + 1] * Sinv;
      c[8 + k]     = __builtin_fmaf(-y0, c[8 + k], c[8 + k]);
      c[8 + k + 1] = __builtin_fmaf(-y1, c[8 + k + 1], c[8 + k + 1]);
      half2v h = pack_f16(y0, y1);
      o1[k] = h[0]; o1[k + 1] = h[1];
    }
    // store-only; rows are consecutive in s (slice r = s>>10 is implicit)
    R8[(size_t)s * 1024 + 2 * t]     = o0;
    R8[(size_t)s * 1024 + 2 * t + 1] = o1;

    a_cur0 = a_nx0; a_cur1 = a_nx1;
    a_nx0 = an0;    a_nx1 = an1;
  }
}

// ---------------- epilogue: out[i][j] = sum_r R[r*1024+i][j] (f32) ----------------
__global__ void softrr_sum8(const __half* __restrict__ Rh, float* __restrict__ out) {
  const int idx8 = blockIdx.x * 256 + threadIdx.x;   // 1M half8 outputs
  const half8* R8 = (const half8*)Rh;
  float acc[8];
  {
    half8 v = R8[idx8];
#pragma unroll
    for (int k = 0; k < 8; ++k) acc[k] = (float)v[k];
  }
#pragma unroll
  for (int r = 1; r < 8; ++r) {
    half8 v = R8[(size_t)r * 1024 * 1024 + idx8];
#pragma unroll
    for (int k = 0; k < 8; ++k) acc[k] += (float)v[k];
  }
  ((float4*)out)[2 * idx8]     = make_float4(acc[0], acc[1], acc[2], acc[3]);
  ((float4*)out)[2 * idx8 + 1] = make_float4(acc[4], acc[5], acc[6], acc[7]);
}

// ---------------- fallback A: RMW scan (R3 path, ws >= 36 MiB) ----------------
__global__ void __launch_bounds__(512) softrr_scan_a(const __half* __restrict__ Ah,
                                                     __half* __restrict__ PIh) {
  const int t = threadIdx.x;
  const int wave = t >> 6;
  const int lane = t & 63;
  __shared__ float sP[2][8];
  const half8* __restrict__ A8 = (const half8*)Ah;
  half8* __restrict__ P8 = (half8*)PIh;
  float c[16];
#pragma unroll
  for (int k = 0; k < 16; ++k) c[k] = 1.0f;
  half8 a0 = A8[2 * t];
  half8 a1 = A8[2 * t + 1];
  half8 p0, p1;
  for (int s = 0; s < STEPS; ++s) {
    const int i = s & (N_ROWS - 1);
    const int r = s >> 10;
    const int in_ = (s + 1) & (N_ROWS - 1);
    const int par = s & 1;
    half8 an0 = A8[in_ * 1024 + 2 * t];
    half8 an1 = A8[in_ * 1024 + 2 * t + 1];
    float e[16];
#pragma unroll
    for (int k = 0; k < 8; ++k) {
      e[k]     = fast_exp2((float)a0[k] * c[k]);
      e[8 + k] = fast_exp2((float)a1[k] * c[8 + k]);
    }
    float l = (((e[0] + e[1]) + (e[2] + e[3])) + ((e[4] + e[5]) + (e[6] + e[7])))
            + (((e[8] + e[9]) + (e[10] + e[11])) + ((e[12] + e[13]) + (e[14] + e[15])));
    l = wave_sum_to_lane63(l);
    if (lane == 63) sP[par][wave] = l;
    BAR_LDS_ONLY();
    float x = (lane < 8) ? sP[par][lane] : 0.0f;
    x = dpp_add<0x111>(x);
    x = dpp_add<0x112>(x);
    x = dpp_add<0x114>(x);
    const float S = __builtin_bit_cast(
        float, __builtin_amdgcn_readlane(__builtin_bit_cast(int, x), 7));
    const float Sinv = fast_rcp(S);
    half8 o0, o1;
#pragma unroll
    for (int k = 0; k < 8; k += 2) {
      float y0 = e[k] * Sinv, y1 = e[k + 1] * Sinv;
      c[k] = __builtin_fmaf(-y0, c[k], c[k]);
      c[k + 1] = __builtin_fmaf(-y1, c[k + 1], c[k + 1]);
      half2v h = pack_f16(y0, y1);
      o0[k] = h[0]; o0[k + 1] = h[1];
    }
#pragma unroll
    for (int k = 0; k < 8; k += 2) {
      float y0 = e[8 + k] * Sinv, y1 = e[8 + k + 1] * Sinv;
      c[8 + k] = __builtin_fmaf(-y0, c[8 + k], c[8 + k]);
      c[8 + k + 1] = __builtin_fmaf(-y1, c[8 + k + 1], c[8 + k + 1]);
      half2v h = pack_f16(y0, y1);
      o1[k] = h[0]; o1[k + 1] = h[1];
    }
    if (r > 0) { o0 = o0 + p0; o1 = o1 + p1; }
    P8[i * 1024 + 2 * t]     = o0;
    P8[i * 1024 + 2 * t + 1] = o1;
    a0 = an0; a1 = an1;
    p0 = P8[in_ * 1024 + 2 * t];
    p1 = P8[in_ * 1024 + 2 * t + 1];
  }
}

__global__ void softrr_cvt(const __half* __restrict__ PIh, float* __restrict__ out) {
  const int idx8 = blockIdx.x * 256 + threadIdx.x;
  half8 p = ((const half8*)PIh)[idx8];
  ((float4*)out)[2 * idx8]     = make_float4((float)p[0], (float)p[1], (float)p[2], (float)p[3]);
  ((float4*)out)[2 * idx8 + 1] = make_float4((float)p[4], (float)p[5], (float)p[6], (float)p[7]);
}

// ---------------- fallback B: f32 direct (tiny ws) ----------------
__global__ void __launch_bounds__(1024) softrr_scan_b(const float* __restrict__ V,
                                                      const float* __restrict__ rmin,
                                                      float* __restrict__ out) {
  const int t = threadIdx.x;
  const int wave = t >> 6;
  const int lane = t & 63;
  __shared__ float partials[2][16];
  __shared__ float smin[N_ROWS];
  smin[t] = rmin[t];
  __syncthreads();
  const float4* __restrict__ V4 = (const float4*)V;
  float4* O4 = (float4*)out;
  float c[8];
#pragma unroll
  for (int k = 0; k < 8; ++k) c[k] = 1.0f;
  float4 va = V4[2 * t], vb = V4[2 * t + 1];
  float4 pa, pb;
  for (int s = 0; s < STEPS; ++s) {
    const int i = s & (N_ROWS - 1);
    const int r = s >> 10;
    const int in_ = (s + 1) & (N_ROWS - 1);
    float4 van = V4[in_ * 2048 + 2 * t];
    float4 vbn = V4[in_ * 2048 + 2 * t + 1];
    const float mn = smin[i];
    const float base = (1.0f - mn) * LOG2E;
    float vv[8] = {va.x, va.y, va.z, va.w, vb.x, vb.y, vb.z, vb.w};
    float e[8];
    float l = 0.0f;
#pragma unroll
    for (int k = 0; k < 8; ++k) {
      float zb = __builtin_fmaf(vv[k], LOG2E, base);
      e[k] = fast_exp2(zb * c[k]);
      l += e[k];
    }
#pragma unroll
    for (int off = 32; off; off >>= 1) l += __shfl_xor(l, off, 64);
    if (lane == 0) partials[s & 1][wave] = l;
    __syncthreads();
    float S = 0.0f;
#pragma unroll
    for (int w = 0; w < 16; ++w) S += partials[s & 1][w];
    const float Sinv = fast_rcp(S);
    float po[8] = {pa.x, pa.y, pa.z, pa.w, pb.x, pb.y, pb.z, pb.w};
    float o[8];
#pragma unroll
    for (int k = 0; k < 8; ++k) {
      float y = e[k] * Sinv;
      c[k] = __builtin_fmaf(-y, c[k], c[k]);
      o[k] = (r > 0) ? (po[k] + y) : y;
    }
    O4[i * 2048 + 2 * t]     = make_float4(o[0], o[1], o[2], o[3]);
    O4[i * 2048 + 2 * t + 1] = make_float4(o[4], o[5], o[6], o[7]);
    va = van; vb = vbn;
    pa = O4[in_ * 2048 + 2 * t];
    pb = O4[in_ * 2048 + 2 * t + 1];
  }
}

extern "C" void kernel_launch(void* const* d_in, const int* in_sizes, int n_in,
                              void* d_out, int out_size, void* d_ws, size_t ws_size,
                              hipStream_t stream) {
  const float* V = (const float*)d_in[0];
  float* out = (float*)d_out;
  float* rmin = (float*)d_ws;

  const size_t A_BYTES = (size_t)N_ROWS * M_COLS * 2;          // 16 MiB
  const size_t R_BYTES = (size_t)STEPS * M_COLS * 2;           // 128 MiB
  const size_t need_nor = 4096 + A_BYTES + R_BYTES;            // ~144 MiB
  const size_t need_rmw = 4096 + A_BYTES + A_BYTES;            // ~32 MiB

  if (ws_size >= need_nor) {
    __half* A = (__half*)((char*)d_ws + 4096);
    __half* R = (__half*)((char*)d_ws + 4096 + A_BYTES);
    softrr_rowmin<<<N_ROWS, 256, 0, stream>>>(V, rmin);
    softrr_prep<<<4096, 256, 0, stream>>>(V, rmin, A);
    softrr_scan_nor<<<1, 512, 0, stream>>>(A, R);
    softrr_sum8<<<4096, 256, 0, stream>>>(R, out);
  } else if (ws_size >= need_rmw) {
    __half* A  = (__half*)((char*)d_ws + 4096);
    __half* PI = (__half*)((char*)d_ws + 4096 + A_BYTES);
    softrr_rowmin<<<N_ROWS, 256, 0, stream>>>(V, rmin);
    softrr_prep<<<4096, 256, 0, stream>>>(V, rmin, A);
    softrr_scan_a<<<1, 512, 0, stream>>>(A, PI);
    softrr_cvt<<<4096, 256, 0, stream>>>(PI, out);
  } else {
    softrr_rowmin<<<N_ROWS, 256, 0, stream>>>(V, rmin);
    softrr_scan_b<<<1, 1024, 0, stream>>>(V, rmin, out);
  }
}